// Round 7
// baseline (301.278 us; speedup 1.0000x reference)
//
#include <hip/hip_runtime.h>
#include <hip/hip_bf16.h>
#include <hip/hip_fp16.h>
#include <math.h>

// Problem constants (fixed by setup_inputs)
#define D_MODEL   256
#define D_FFN     1024
#define N_LEVELS  4
#define N_HEADS   8
#define N_POINTS  4
#define BATCH     2
#define LQ        8192
#define S_TOTAL   21760            // 128*128 + 64*64 + 32*32 + 16*16
#define M_Q       (BATCH*LQ)       // 16384
#define M_V       (BATCH*S_TOTAL)  // 43520
#define VTILES    (M_V/128)        // 340

typedef __attribute__((ext_vector_type(8))) short bf16x8;   // 8 bf16 = 4 VGPRs
typedef __attribute__((ext_vector_type(4))) float floatx4;  // mfma C/D

struct alignas(8)  bh4 { __hip_bfloat16 a, b, c, d; };
struct alignas(16) bh8 { __hip_bfloat16 v[8]; };

__device__ __forceinline__ void gld_lds16(const void* g, void* l) {
    __builtin_amdgcn_global_load_lds(
        (const __attribute__((address_space(1))) void*)g,
        (__attribute__((address_space(3))) void*)l, 16, 0, 0);
}

__device__ __forceinline__ bh8 pack8(float4 a, float4 b) {
    bh8 o;
    o.v[0] = __float2bfloat16(a.x); o.v[1] = __float2bfloat16(a.y);
    o.v[2] = __float2bfloat16(a.z); o.v[3] = __float2bfloat16(a.w);
    o.v[4] = __float2bfloat16(b.x); o.v[5] = __float2bfloat16(b.y);
    o.v[6] = __float2bfloat16(b.z); o.v[7] = __float2bfloat16(b.w);
    return o;
}

// ---------------------------------------------------------------------------
// Core bf16 MFMA K-loop, double-buffered LDS, ONE barrier per K-iteration.
// Block tile BM x BN, 4 waves on M. v_mfma_f32_16x16x32_bf16, BK=32,
// global_load_lds(16B) staging. Bt is [N][ldb]. A is bf16 [M][lda].
// ---------------------------------------------------------------------------
template<int BM, int BN, int K>
__device__ __forceinline__ void gemm_core(const __hip_bfloat16* __restrict__ A,
                                          const __hip_bfloat16* __restrict__ Bt,
                                          int row0, int nb0, int lda, int ldb,
                                          short* As, short* Bs,
                                          floatx4 (&acc)[BM/64][BN/16])
{
    constexpr int NT  = BN / 16;
    constexpr int AF  = BM / 64;
    constexpr int BCH = BN / 64;
    constexpr int NIT = K / 32;

    const int tid  = threadIdx.x;
    const int w    = tid >> 6;
    const int lane = tid & 63;
    const int quad = lane >> 4;
    const int l15  = lane & 15;
    const size_t ldaB = (size_t)lda * 2, ldbB = (size_t)ldb * 2;

    const char* gA[AF]; int lA[AF];
#pragma unroll
    for (int i = 0; i < AF; i++) {
        int o = (w * AF + i) * 1024 + lane * 16;
        gA[i] = (const char*)A + (size_t)(row0 + (o >> 6)) * ldaB + (o & 63);
        lA[i] = (w * AF + i) * 512;
    }
    const char* gB[BCH]; int lB[BCH];
#pragma unroll
    for (int j = 0; j < BCH; j++) {
        int o = (w * BCH + j) * 1024 + lane * 16;
        gB[j] = (const char*)Bt + (size_t)(nb0 + (o >> 6)) * ldbB + (o & 63);
        lB[j] = (w * BCH + j) * 512;
    }

    // prologue: stage K-tile 0 into buffer 0
#pragma unroll
    for (int i = 0; i < AF; i++)  gld_lds16(gA[i], &As[lA[i]]);
#pragma unroll
    for (int j = 0; j < BCH; j++) gld_lds16(gB[j], &Bs[lB[j]]);

#pragma unroll 8
    for (int it = 0; it < NIT; ++it) {
        __syncthreads();
        const int cb = it & 1;
        if (it + 1 < NIT) {
            const size_t kb = (size_t)(it + 1) * 64;   // 32 k * 2 B
            const int nb = cb ^ 1;
#pragma unroll
            for (int i = 0; i < AF; i++)  gld_lds16(gA[i] + kb, &As[nb * BM * 32 + lA[i]]);
#pragma unroll
            for (int j = 0; j < BCH; j++) gld_lds16(gB[j] + kb, &Bs[nb * BN * 32 + lB[j]]);
        }
        const short* Ab = &As[cb * BM * 32];
        const short* Bb = &Bs[cb * BN * 32];
        bf16x8 af[AF];
#pragma unroll
        for (int mi = 0; mi < AF; mi++)
            af[mi] = *(const bf16x8*)&Ab[(w * (AF * 16) + mi * 16 + l15) * 32 + quad * 8];
#pragma unroll
        for (int ni = 0; ni < NT; ni++) {
            bf16x8 bfr = *(const bf16x8*)&Bb[(ni * 16 + l15) * 32 + quad * 8];
#pragma unroll
            for (int mi = 0; mi < AF; mi++)
                acc[mi][ni] = __builtin_amdgcn_mfma_f32_16x16x32_bf16(af[mi], bfr, acc[mi][ni], 0, 0, 0);
        }
    }
}

// ---------------------------------------------------------------------------
// Variant: A is f32 (optionally A+A2), converted to bf16 in-register during
// staging (manual ds_write_b128 path). BM=BN=128 fixed. Kills the separate
// f32->bf16 conversion pass over src / (tgt+qpos).
// ---------------------------------------------------------------------------
template<int K, bool ADD>
__device__ __forceinline__ void gemm_core_cvtA(const float* __restrict__ Af,
                                               const float* __restrict__ A2f,
                                               const __hip_bfloat16* __restrict__ Bt,
                                               int row0, int nb0, int lda, int ldb,
                                               short* As, short* Bs,
                                               floatx4 (&acc)[2][8])
{
    constexpr int NIT = K / 32;
    const int tid  = threadIdx.x;
    const int w    = tid >> 6;
    const int lane = tid & 63;
    const int quad = lane >> 4;
    const int l15  = lane & 15;

    // A staging: thread covers row arow, 16 consecutive k's (two halves/row)
    const int arow = tid >> 1, akb = (tid & 1) * 16;
    const float* gA  = Af + (size_t)(row0 + arow) * lda + akb;
    const float* gA2 = ADD ? (A2f + (size_t)(row0 + arow) * lda + akb) : nullptr;
    const int aoff = arow * 32 + akb;

    const size_t ldbB = (size_t)ldb * 2;
    const char* gB[2]; int lB[2];
#pragma unroll
    for (int j = 0; j < 2; j++) {
        int o = (w * 2 + j) * 1024 + lane * 16;
        gB[j] = (const char*)Bt + (size_t)(nb0 + (o >> 6)) * ldbB + (o & 63);
        lB[j] = (w * 2 + j) * 512;
    }

    float4 fv[4];
    // prologue: tile 0 -> regs, B tile 0 -> LDS buf0
#pragma unroll
    for (int i = 0; i < 4; i++) {
        fv[i] = *(const float4*)(gA + i * 4);
        if (ADD) {
            float4 t = *(const float4*)(gA2 + i * 4);
            fv[i].x += t.x; fv[i].y += t.y; fv[i].z += t.z; fv[i].w += t.w;
        }
    }
#pragma unroll
    for (int j = 0; j < 2; j++) gld_lds16(gB[j], &Bs[lB[j]]);
    *(bh8*)&As[aoff]     = pack8(fv[0], fv[1]);
    *(bh8*)&As[aoff + 8] = pack8(fv[2], fv[3]);

#pragma unroll 8
    for (int it = 0; it < NIT; ++it) {
        __syncthreads();
        const int cb = it & 1;
        const bool more = (it + 1 < NIT);
        if (more) {
            const int kt = (it + 1) * 32;
#pragma unroll
            for (int i = 0; i < 4; i++) {
                fv[i] = *(const float4*)(gA + kt + i * 4);
                if (ADD) {
                    float4 t = *(const float4*)(gA2 + kt + i * 4);
                    fv[i].x += t.x; fv[i].y += t.y; fv[i].z += t.z; fv[i].w += t.w;
                }
            }
#pragma unroll
            for (int j = 0; j < 2; j++)
                gld_lds16(gB[j] + (size_t)(it + 1) * 64, &Bs[(cb ^ 1) * 128 * 32 + lB[j]]);
        }
        const short* Ab = &As[cb * 128 * 32];
        const short* Bb = &Bs[cb * 128 * 32];
        bf16x8 af[2];
        af[0] = *(const bf16x8*)&Ab[(w * 32      + l15) * 32 + quad * 8];
        af[1] = *(const bf16x8*)&Ab[(w * 32 + 16 + l15) * 32 + quad * 8];
#pragma unroll
        for (int ni = 0; ni < 8; ni++) {
            bf16x8 bfr = *(const bf16x8*)&Bb[(ni * 16 + l15) * 32 + quad * 8];
            acc[0][ni] = __builtin_amdgcn_mfma_f32_16x16x32_bf16(af[0], bfr, acc[0][ni], 0, 0, 0);
            acc[1][ni] = __builtin_amdgcn_mfma_f32_16x16x32_bf16(af[1], bfr, acc[1][ni], 0, 0, 0);
        }
        if (more) {
            short* dst = &As[(cb ^ 1) * 128 * 32 + aoff];
            *(bh8*)dst       = pack8(fv[0], fv[1]);
            *(bh8*)(dst + 8) = pack8(fv[2], fv[3]);
        }
    }
}

// ---------------------------------------------------------------------------
// Generic GEMM. EPI: 0 = f32 (+bias); 1 = bf16 (+bias); 2 = relu -> bf16.
// blockIdx.z: K-split chunk — A/Bt advance by z*K, outf by z*zStride.
// ---------------------------------------------------------------------------
template<int BM, int BN, int K, int EPI>
__global__ __launch_bounds__(256)
void mfma_gemm(const __hip_bfloat16* __restrict__ A,
               const __hip_bfloat16* __restrict__ Bt,
               const float* __restrict__ bias,
               float* __restrict__ outf, __hip_bfloat16* __restrict__ outb,
               int lda, int ldb, int ldOut, long zStride)
{
    constexpr int NT = BN / 16, AF = BM / 64;
    __shared__ alignas(16) short As[2 * BM * 32];
    __shared__ alignas(16) short Bs[2 * BN * 32];

    const int tid = threadIdx.x, w = tid >> 6, lane = tid & 63;
    const int quad = lane >> 4, l15 = lane & 15;
    const int row0 = blockIdx.x * BM, nb0 = blockIdx.y * BN;
    const int z = blockIdx.z;

    floatx4 acc[AF][NT];
#pragma unroll
    for (int mi = 0; mi < AF; mi++)
#pragma unroll
        for (int ni = 0; ni < NT; ni++) acc[mi][ni] = (floatx4){0.f, 0.f, 0.f, 0.f};

    gemm_core<BM, BN, K>(A + (size_t)z * K, Bt + (size_t)z * K,
                         row0, nb0, lda, ldb, As, Bs, acc);

    float bias_c[NT];
#pragma unroll
    for (int ni = 0; ni < NT; ni++) bias_c[ni] = bias ? bias[nb0 + ni * 16 + l15] : 0.f;

    float* of = outf + (size_t)z * zStride;
#pragma unroll
    for (int mi = 0; mi < AF; mi++)
#pragma unroll
        for (int r = 0; r < 4; r++) {
            int row = row0 + w * (AF * 16) + mi * 16 + quad * 4 + r;
            size_t rb = (size_t)row * ldOut + nb0;
#pragma unroll
            for (int ni = 0; ni < NT; ni++) {
                float v = acc[mi][ni][r] + bias_c[ni];
                if (EPI == 2)      outb[rb + ni * 16 + l15] = __float2bfloat16(fmaxf(v, 0.f));
                else if (EPI == 1) outb[rb + ni * 16 + l15] = __float2bfloat16(v);
                else               of[rb + ni * 16 + l15] = v;
            }
        }
}

// ---------------------------------------------------------------------------
// Merged value-projection + off/attn GEMM, f32 A with fused cvt staging.
// grid = (VTILES + 128, 3). x < VTILES: value = src @ Wv (y<2, bf16 out).
// x >= VTILES: (tgt+qpos) @ [W_off^T ++ W_attn^T] (y<2 off f32; y==2 softmax).
// ---------------------------------------------------------------------------
__global__ __launch_bounds__(256)
void mfma_gemm_vq(const float* __restrict__ src,
                  const __hip_bfloat16* __restrict__ Wvt,
                  const float* __restrict__ b_value,
                  __hip_bfloat16* __restrict__ valueb,
                  const float* __restrict__ tgt, const float* __restrict__ qpos,
                  const __hip_bfloat16* __restrict__ Woat,
                  const float* __restrict__ b_off, const float* __restrict__ b_attn,
                  float* __restrict__ offb, float* __restrict__ attnb)
{
    __shared__ alignas(16) short As[2 * 128 * 32];
    __shared__ alignas(16) short Bs[2 * 128 * 32];

    const bool isV = blockIdx.x < VTILES;
    if (isV && blockIdx.y == 2) return;

    const int tid = threadIdx.x, w = tid >> 6, lane = tid & 63;
    const int quad = lane >> 4, l15 = lane & 15;
    const int nb0 = blockIdx.y * 128;

    floatx4 acc[2][8];
#pragma unroll
    for (int mi = 0; mi < 2; mi++)
#pragma unroll
        for (int ni = 0; ni < 8; ni++) acc[mi][ni] = (floatx4){0.f, 0.f, 0.f, 0.f};

    if (isV) {
        const int row0 = blockIdx.x * 128;
        gemm_core_cvtA<256, false>(src, nullptr, Wvt, row0, nb0, 256, 256, As, Bs, acc);
        float bias_c[8];
#pragma unroll
        for (int ni = 0; ni < 8; ni++) bias_c[ni] = b_value[nb0 + ni * 16 + l15];
#pragma unroll
        for (int mi = 0; mi < 2; mi++)
#pragma unroll
            for (int r = 0; r < 4; r++) {
                int row = row0 + w * 32 + mi * 16 + quad * 4 + r;
                size_t rb = (size_t)row * 256 + nb0;
#pragma unroll
                for (int ni = 0; ni < 8; ni++)
                    valueb[rb + ni * 16 + l15] = __float2bfloat16(acc[mi][ni][r] + bias_c[ni]);
            }
        return;
    }

    const int row0 = (blockIdx.x - VTILES) * 128;
    gemm_core_cvtA<256, true>(tgt, qpos, Woat, row0, nb0, 256, 256, As, Bs, acc);

    if (blockIdx.y < 2) {    // offsets, f32, ld 256
        float bias_c[8];
#pragma unroll
        for (int ni = 0; ni < 8; ni++) bias_c[ni] = b_off[nb0 + ni * 16 + l15];
#pragma unroll
        for (int mi = 0; mi < 2; mi++)
#pragma unroll
            for (int r = 0; r < 4; r++) {
                int row = row0 + w * 32 + mi * 16 + quad * 4 + r;
                size_t rb = (size_t)row * 256 + nb0;
#pragma unroll
                for (int ni = 0; ni < 8; ni++)
                    offb[rb + ni * 16 + l15] = acc[mi][ni][r] + bias_c[ni];
            }
    } else {                 // attn: group-softmax(16) -> ld 128
        float bias_c[8];
#pragma unroll
        for (int ni = 0; ni < 8; ni++) bias_c[ni] = b_attn[ni * 16 + l15];
#pragma unroll
        for (int mi = 0; mi < 2; mi++)
#pragma unroll
            for (int r = 0; r < 4; r++) {
                int row = row0 + w * 32 + mi * 16 + quad * 4 + r;
                size_t rb = (size_t)row * 128;
#pragma unroll
                for (int ni = 0; ni < 8; ni++) {
                    float v = acc[mi][ni][r] + bias_c[ni];
                    float m = v;
#pragma unroll
                    for (int msk = 1; msk <= 8; msk <<= 1) m = fmaxf(m, __shfl_xor(m, msk));
                    float e = __expf(v - m);
                    float ssum = e;
#pragma unroll
                    for (int msk = 1; msk <= 8; msk <<= 1) ssum += __shfl_xor(ssum, msk);
                    attnb[rb + ni * 16 + l15] = e / ssum;
                }
            }
    }
}

// ---------------------------------------------------------------------------
// Residual + LayerNorm, one wave per 256-col row.
// v = resid + in1 (+ in2) (+ bias); out f32 (+ optional bf16 copy).
// B1: in1 is bf16 (in1b) instead of f32 (in1f).
// ---------------------------------------------------------------------------
template<bool B1>
__global__ __launch_bounds__(256)
void ln_kernel(const float* __restrict__ in1f, const __hip_bfloat16* __restrict__ in1b,
               const float* __restrict__ in2,
               const float* __restrict__ resid, const float* __restrict__ bias,
               const float* __restrict__ g, const float* __restrict__ b,
               float* __restrict__ outf, __hip_bfloat16* __restrict__ outb)
{
    const int row  = blockIdx.x * 4 + (threadIdx.x >> 6);
    const int lane = threadIdx.x & 63;
    const size_t rb = (size_t)row * 256 + lane * 4;

    float4 v = *(const float4*)(resid + rb);
    if (B1) {
        bh4 a = *(const bh4*)(in1b + rb);
        v.x += __bfloat162float(a.a); v.y += __bfloat162float(a.b);
        v.z += __bfloat162float(a.c); v.w += __bfloat162float(a.d);
    } else {
        float4 a = *(const float4*)(in1f + rb);
        v.x += a.x; v.y += a.y; v.z += a.z; v.w += a.w;
    }
    if (in2) {
        float4 c = *(const float4*)(in2 + rb);
        v.x += c.x; v.y += c.y; v.z += c.z; v.w += c.w;
    }
    if (bias) {
        float4 c = *(const float4*)(bias + lane * 4);
        v.x += c.x; v.y += c.y; v.z += c.z; v.w += c.w;
    }
    float s  = v.x + v.y + v.z + v.w;
    float sq = v.x * v.x + v.y * v.y + v.z * v.z + v.w * v.w;
#pragma unroll
    for (int msk = 1; msk <= 32; msk <<= 1) {
        s += __shfl_xor(s, msk); sq += __shfl_xor(sq, msk);
    }
    float mean = s * (1.f / 256.f);
    float var  = sq * (1.f / 256.f) - mean * mean;
    float rstd = rsqrtf(var + 1e-5f);
    float4 gg = *(const float4*)(g + lane * 4);
    float4 bb = *(const float4*)(b + lane * 4);
    float4 o;
    o.x = (v.x - mean) * rstd * gg.x + bb.x;
    o.y = (v.y - mean) * rstd * gg.y + bb.y;
    o.z = (v.z - mean) * rstd * gg.z + bb.z;
    o.w = (v.w - mean) * rstd * gg.w + bb.w;
    *(float4*)(outf + rb) = o;
    if (outb)
        *(bh4*)(outb + rb) = { __float2bfloat16(o.x), __float2bfloat16(o.y),
                               __float2bfloat16(o.z), __float2bfloat16(o.w) };
}

// ---------------------------------------------------------------------------
// Prep: weight transpose + f32->bf16 only (736 tiles of 32x32)
// ---------------------------------------------------------------------------
__global__ __launch_bounds__(256)
void prep_kernel(const float* w0, const float* w1, const float* w2,
                 const float* w3, const float* w4, const float* w5,
                 __hip_bfloat16* o0, __hip_bfloat16* o1, __hip_bfloat16* o2,
                 __hip_bfloat16* o3, __hip_bfloat16* o4, __hip_bfloat16* o5)
{
    int t = blockIdx.x;
    const float* s; __hip_bfloat16* dst; int Kd, Nd, tl;
    if      (t < 64)  { s = w0; dst = o0; Kd = 256;  Nd = 256;  tl = t; }
    else if (t < 128) { s = w1; dst = o1; Kd = 256;  Nd = 256;  tl = t - 64; }
    else if (t < 160) { s = w2; dst = o2; Kd = 256;  Nd = 128;  tl = t - 128; }
    else if (t < 224) { s = w3; dst = o3; Kd = 256;  Nd = 256;  tl = t - 160; }
    else if (t < 480) { s = w4; dst = o4; Kd = 256;  Nd = 1024; tl = t - 224; }
    else              { s = w5; dst = o5; Kd = 1024; Nd = 256;  tl = t - 480; }
    int ntn = Nd >> 5;
    int kt = tl / ntn, nt = tl - kt * ntn;
    __shared__ float T[32][33];
    int tx = threadIdx.x & 31, ty = threadIdx.x >> 5;
#pragma unroll
    for (int i = 0; i < 4; i++) {
        int k = kt * 32 + ty + i * 8;
        T[tx][ty + i * 8] = s[(size_t)k * Nd + nt * 32 + tx];
    }
    __syncthreads();
#pragma unroll
    for (int i = 0; i < 4; i++) {
        int n = nt * 32 + ty + i * 8;
        dst[(size_t)n * Kd + kt * 32 + tx] = __float2bfloat16(T[ty + i * 8][tx]);
    }
}

// ---------------------------------------------------------------------------
// Deformable bilinear sampling v5. Block = 8 queries, LDS 4B/entry
// ([31:16] pixel row, [15:0] weight fp16), stride-65 layout (conflict-free).
// Phase 2: thread=(ql,h,d4) gathers 8 channels per 16B load, EXPLICIT
// 16-deep load batching for latency tolerance (prev: compiler chose ~6-8).
// ---------------------------------------------------------------------------
#define QB 8
__global__ __launch_bounds__(256, 4)
void sample_kernel(const float* __restrict__ refp, const float* __restrict__ offb,
                   const float* __restrict__ attn,
                   const __hip_bfloat16* __restrict__ value,
                   __hip_bfloat16* __restrict__ tgt2)
{
    __shared__ unsigned spk[64 * 65];       // [sc=lp*4+c][g=ql*8+h]

    const int q0  = blockIdx.x * QB;
    const int tid = threadIdx.x;

    // ---- phase 1 ----
#pragma unroll
    for (int k = 0; k < 4; k++) {
        const int it = tid + k * 256;        // (ql,h,lp)
        const int ql = it >> 7, h = (it >> 4) & 7, lp = it & 15;
        const int l = lp >> 2, p = lp & 3;
        const int q = q0 + ql, b = q >> 13;
        const int Wl = 128 >> l;
        const int LST = (l == 0) ? 0 : (l == 1) ? 16384 : (l == 2) ? 20480 : 21504;

        const float rx = refp[((size_t)q * N_LEVELS + l) * 2 + 0];
        const float ry = refp[((size_t)q * N_LEVELS + l) * 2 + 1];
        const float ox = offb[(size_t)q * 256 + h * 32 + l * 8 + p * 2 + 0];
        const float oy = offb[(size_t)q * 256 + h * 32 + l * 8 + p * 2 + 1];
        const float a  = attn[(size_t)q * 128 + h * 16 + lp];

        const float x = rx * Wl - 0.5f + ox;
        const float y = ry * Wl - 0.5f + oy;
        const float x0f = floorf(x), y0f = floorf(y);
        const float wx = x - x0f, wy = y - y0f;
        const int ix = (int)x0f, iy = (int)y0f;
        const int base = b * S_TOTAL + LST;
        const int g = ql * 8 + h;
        const float cw[4] = {(1.f - wx) * (1.f - wy) * a, wx * (1.f - wy) * a,
                             (1.f - wx) * wy * a,         wx * wy * a};
#pragma unroll
        for (int c = 0; c < 4; c++) {
            const int xi = ix + (c & 1), yi = iy + (c >> 1);
            const bool valid = ((unsigned)xi < (unsigned)Wl) && ((unsigned)yi < (unsigned)Wl);
            const unsigned pix = valid ? (unsigned)(base + yi * Wl + xi) : (unsigned)base;
            const __half hw = __float2half(valid ? cw[c] : 0.f);
            spk[(lp * 4 + c) * 65 + g] = (pix << 16) | (unsigned)__half_as_ushort(hw);
        }
    }
    __syncthreads();

    // ---- phase 2: 4 batches of 16 gathers, loads issued 16-deep ----
    const int ql = tid >> 5, h = (tid >> 2) & 7, d4 = tid & 3;
    const int q = q0 + ql, g = ql * 8 + h;
    const int c0 = h * 32 + d4 * 8;
    const char* vb = (const char*)value + (size_t)c0 * 2;

    float ac[8] = {0.f, 0.f, 0.f, 0.f, 0.f, 0.f, 0.f, 0.f};
#pragma unroll
    for (int ch = 0; ch < 4; ch++) {
        unsigned us[16];
#pragma unroll
        for (int j = 0; j < 16; j++) us[j] = spk[(ch * 16 + j) * 65 + g];
        uint4 rv[16];
#pragma unroll
        for (int j = 0; j < 16; j++)
            rv[j] = *(const uint4*)(vb + ((size_t)(us[j] >> 16) << 9));
#pragma unroll
        for (int j = 0; j < 16; j++) {
            float wv = __half2float(__ushort_as_half((unsigned short)(us[j] & 0xffffu)));
            ac[0] += wv * __uint_as_float(rv[j].x << 16);
            ac[1] += wv * __uint_as_float(rv[j].x & 0xffff0000u);
            ac[2] += wv * __uint_as_float(rv[j].y << 16);
            ac[3] += wv * __uint_as_float(rv[j].y & 0xffff0000u);
            ac[4] += wv * __uint_as_float(rv[j].z << 16);
            ac[5] += wv * __uint_as_float(rv[j].z & 0xffff0000u);
            ac[6] += wv * __uint_as_float(rv[j].w << 16);
            ac[7] += wv * __uint_as_float(rv[j].w & 0xffff0000u);
        }
    }
    bh8 o;
#pragma unroll
    for (int i = 0; i < 8; i++) o.v[i] = __float2bfloat16(ac[i]);
    *(bh8*)(tgt2 + (size_t)q * 256 + c0) = o;
}

// ---------------------------------------------------------------------------
extern "C" void kernel_launch(void* const* d_in, const int* in_sizes, int n_in,
                              void* d_out, int out_size, void* d_ws, size_t ws_size,
                              hipStream_t stream) {
    const float* tgt     = (const float*)d_in[0];
    const float* qpos    = (const float*)d_in[1];
    const float* refp    = (const float*)d_in[2];
    const float* src     = (const float*)d_in[3];
    const float* W_value = (const float*)d_in[6];
    const float* b_value = (const float*)d_in[7];
    const float* W_off   = (const float*)d_in[8];
    const float* b_off   = (const float*)d_in[9];
    const float* W_attn  = (const float*)d_in[10];
    const float* b_attn  = (const float*)d_in[11];
    const float* W_out   = (const float*)d_in[12];
    const float* b_out   = (const float*)d_in[13];
    const float* ln1_g   = (const float*)d_in[14];
    const float* ln1_b   = (const float*)d_in[15];
    const float* W1      = (const float*)d_in[16];
    const float* b1      = (const float*)d_in[17];
    const float* W2      = (const float*)d_in[18];
    const float* b2      = (const float*)d_in[19];
    const float* ln3_g   = (const float*)d_in[20];
    const float* ln3_b   = (const float*)d_in[21];
    float* out = (float*)d_out;

    // workspace layout
    char* p = (char*)d_ws;
    auto nxt = [&](size_t b) { char* r = p; p += (b + 255) & ~(size_t)255; return r; };
    __hip_bfloat16* Wvt    = (__hip_bfloat16*)nxt((size_t)256 * 256 * 2);
    __hip_bfloat16* Woat   = (__hip_bfloat16*)nxt((size_t)384 * 256 * 2);
    __hip_bfloat16* Woutt  = (__hip_bfloat16*)nxt((size_t)256 * 256 * 2);
    __hip_bfloat16* W1t    = (__hip_bfloat16*)nxt((size_t)1024 * 256 * 2);
    __hip_bfloat16* W2t    = (__hip_bfloat16*)nxt((size_t)256 * 1024 * 2);
    __hip_bfloat16* valueb = (__hip_bfloat16*)nxt((size_t)M_V * 256 * 2);  // dead after sampler
    float*          offb   = (float*)nxt((size_t)M_Q * 256 * 4);           // dead after sampler
    float*          attnb  = (float*)nxt((size_t)M_Q * 128 * 4);
    __hip_bfloat16* tgt2b  = (__hip_bfloat16*)nxt((size_t)M_Q * 256 * 2);
    __hip_bfloat16* t2ob   = (__hip_bfloat16*)nxt((size_t)M_Q * 256 * 2);
    float*          x      = (float*)nxt((size_t)M_Q * 256 * 4);
    __hip_bfloat16* xb     = (__hip_bfloat16*)nxt((size_t)M_Q * 256 * 2);
    __hip_bfloat16* hb     = (__hip_bfloat16*)nxt((size_t)M_Q * 1024 * 2);
    // FFN2 split-K partials overlay [valueb, valueb+33.6MB): valueb (22.28 MB,
    // 256B-aligned size -> offb is directly contiguous) + offb (16.78 MB) —
    // both dead after the sampler. p1 = p0 + zStride exactly.
    float* p0 = (float*)valueb;
    float* p1 = p0 + (size_t)M_Q * 256;

    dim3 blk(256);

    // 0) prep: weight transpose+cvt only
    prep_kernel<<<dim3(736), blk, 0, stream>>>(
        W_value, W_off, W_attn, W_out, W1, W2,
        Wvt, Woat, Woat + 256 * 256, Woutt, W1t, W2t);

    // 1) value GEMM ++ off/attn GEMM (f32 A, fused cvt staging)
    mfma_gemm_vq<<<dim3(VTILES + M_Q / 128, 3), blk, 0, stream>>>(
        src, Wvt, b_value, valueb, tgt, qpos, Woat, b_off, b_attn, offb, attnb);

    // 2) deformable sampling -> tgt2 (bf16)
    sample_kernel<<<dim3(M_Q / QB), blk, 0, stream>>>(refp, offb, attnb, valueb, tgt2b);

    // 3) t2o = tgt2 @ W_out + b_out -> bf16  (512 blocks)
    mfma_gemm<64, 128, 256, 1><<<dim3(M_Q / 64, 2), blk, 0, stream>>>(
        tgt2b, Woutt, b_out, nullptr, t2ob, 256, 256, 256, 0);

    // 4) x = LN1(tgt + t2o) -> f32 + bf16
    ln_kernel<true><<<dim3(M_Q / 4), blk, 0, stream>>>(
        nullptr, t2ob, nullptr, tgt, nullptr, ln1_g, ln1_b, x, xb);

    // 5) h = relu(x @ W1 + b1) -> bf16  (1024 blocks)
    mfma_gemm<128, 128, 256, 2><<<dim3(M_Q / 128, 8), blk, 0, stream>>>(
        xb, W1t, b1, nullptr, hb, 256, 256, 1024, 0);

    // 6) FFN2 split-K: p[z] = h[:, z*512:+512] @ W2t[:, z*512:+512]  (1024 blocks)
    mfma_gemm<64, 128, 512, 0><<<dim3(M_Q / 64, 2, 2), blk, 0, stream>>>(
        hb, W2t, nullptr, p0, nullptr, 1024, 1024, 256, (long)M_Q * 256);

    // 7) out = LN3(x + p0 + p1 + b2) -> f32
    ln_kernel<false><<<dim3(M_Q / 4), blk, 0, stream>>>(
        p0, nullptr, p1, x, b2, ln3_g, ln3_b, out, nullptr);
}

// Round 8
// 299.562 us; speedup vs baseline: 1.0057x; 1.0057x over previous
//
#include <hip/hip_runtime.h>
#include <hip/hip_bf16.h>
#include <hip/hip_fp16.h>
#include <math.h>

// Problem constants (fixed by setup_inputs)
#define D_MODEL   256
#define D_FFN     1024
#define N_LEVELS  4
#define N_HEADS   8
#define N_POINTS  4
#define BATCH     2
#define LQ        8192
#define S_TOTAL   21760            // 128*128 + 64*64 + 32*32 + 16*16
#define M_Q       (BATCH*LQ)       // 16384
#define M_V       (BATCH*S_TOTAL)  // 43520
#define VTILES    (M_V/128)        // 340

typedef __attribute__((ext_vector_type(8))) short bf16x8;   // 8 bf16 = 4 VGPRs
typedef __attribute__((ext_vector_type(4))) float floatx4;  // mfma C/D

struct alignas(8)  bh4 { __hip_bfloat16 a, b, c, d; };
struct alignas(16) bh8 { __hip_bfloat16 v[8]; };

__device__ __forceinline__ void gld_lds16(const void* g, void* l) {
    __builtin_amdgcn_global_load_lds(
        (const __attribute__((address_space(1))) void*)g,
        (__attribute__((address_space(3))) void*)l, 16, 0, 0);
}

__device__ __forceinline__ bh4 pack4(float4 a) {
    return { __float2bfloat16(a.x), __float2bfloat16(a.y),
             __float2bfloat16(a.z), __float2bfloat16(a.w) };
}

// ---------------------------------------------------------------------------
// Core bf16 MFMA K-loop, double-buffered LDS, ONE barrier per K-iteration.
// Block tile BM x BN, 4 waves on M. v_mfma_f32_16x16x32_bf16, BK=32,
// global_load_lds(16B) staging. Bt is [N][ldb]. A is bf16 [M][lda].
// ---------------------------------------------------------------------------
template<int BM, int BN, int K>
__device__ __forceinline__ void gemm_core(const __hip_bfloat16* __restrict__ A,
                                          const __hip_bfloat16* __restrict__ Bt,
                                          int row0, int nb0, int lda, int ldb,
                                          short* As, short* Bs,
                                          floatx4 (&acc)[BM/64][BN/16])
{
    constexpr int NT  = BN / 16;
    constexpr int AF  = BM / 64;
    constexpr int BCH = BN / 64;
    constexpr int NIT = K / 32;

    const int tid  = threadIdx.x;
    const int w    = tid >> 6;
    const int lane = tid & 63;
    const int quad = lane >> 4;
    const int l15  = lane & 15;
    const size_t ldaB = (size_t)lda * 2, ldbB = (size_t)ldb * 2;

    const char* gA[AF]; int lA[AF];
#pragma unroll
    for (int i = 0; i < AF; i++) {
        int o = (w * AF + i) * 1024 + lane * 16;
        gA[i] = (const char*)A + (size_t)(row0 + (o >> 6)) * ldaB + (o & 63);
        lA[i] = (w * AF + i) * 512;
    }
    const char* gB[BCH]; int lB[BCH];
#pragma unroll
    for (int j = 0; j < BCH; j++) {
        int o = (w * BCH + j) * 1024 + lane * 16;
        gB[j] = (const char*)Bt + (size_t)(nb0 + (o >> 6)) * ldbB + (o & 63);
        lB[j] = (w * BCH + j) * 512;
    }

    // prologue: stage K-tile 0 into buffer 0
#pragma unroll
    for (int i = 0; i < AF; i++)  gld_lds16(gA[i], &As[lA[i]]);
#pragma unroll
    for (int j = 0; j < BCH; j++) gld_lds16(gB[j], &Bs[lB[j]]);

#pragma unroll 8
    for (int it = 0; it < NIT; ++it) {
        __syncthreads();
        const int cb = it & 1;
        if (it + 1 < NIT) {
            const size_t kb = (size_t)(it + 1) * 64;   // 32 k * 2 B
            const int nb = cb ^ 1;
#pragma unroll
            for (int i = 0; i < AF; i++)  gld_lds16(gA[i] + kb, &As[nb * BM * 32 + lA[i]]);
#pragma unroll
            for (int j = 0; j < BCH; j++) gld_lds16(gB[j] + kb, &Bs[nb * BN * 32 + lB[j]]);
        }
        const short* Ab = &As[cb * BM * 32];
        const short* Bb = &Bs[cb * BN * 32];
        bf16x8 af[AF];
#pragma unroll
        for (int mi = 0; mi < AF; mi++)
            af[mi] = *(const bf16x8*)&Ab[(w * (AF * 16) + mi * 16 + l15) * 32 + quad * 8];
#pragma unroll
        for (int ni = 0; ni < NT; ni++) {
            bf16x8 bfr = *(const bf16x8*)&Bb[(ni * 16 + l15) * 32 + quad * 8];
#pragma unroll
            for (int mi = 0; mi < AF; mi++)
                acc[mi][ni] = __builtin_amdgcn_mfma_f32_16x16x32_bf16(af[mi], bfr, acc[mi][ni], 0, 0, 0);
        }
    }
}

// ---------------------------------------------------------------------------
// Variant: A is f32 (optionally A+A2), converted to bf16 during staging.
// v2 — COALESCED: instruction j loads tile byte j*4096 + tid*16, so
// consecutive lanes read consecutive 16B (8 full 128B lines per wave-instr;
// round-7 v1 scattered 2 lanes/line across 32 lines -> 4x TA work, 1.5 TB/s).
// Thread's piece j = row (j*32 + tid/8), f32 k-bytes (tid&7)*16 (4 k's).
// Pack -> bh4, ds_write_b64 at As[r*32 + (tid&7)*4]. BM=BN=128 fixed.
// ---------------------------------------------------------------------------
template<int K, bool ADD>
__device__ __forceinline__ void gemm_core_cvtA(const float* __restrict__ Af,
                                               const float* __restrict__ A2f,
                                               const __hip_bfloat16* __restrict__ Bt,
                                               int row0, int nb0, int lda, int ldb,
                                               short* As, short* Bs,
                                               floatx4 (&acc)[2][8])
{
    constexpr int NIT = K / 32;
    const int tid  = threadIdx.x;
    const int w    = tid >> 6;
    const int lane = tid & 63;
    const int quad = lane >> 4;
    const int l15  = lane & 15;

    // A staging: piece j -> row rj = j*32 + (tid>>3), k0 = (tid&7)*4
    const int rA  = tid >> 3;            // base row (j adds 32j)
    const int k0  = (tid & 7) * 4;       // f32 k offset
    const float* gA  = Af + (size_t)(row0 + rA) * lda + k0;
    const float* gA2 = ADD ? (A2f + (size_t)(row0 + rA) * lda + k0) : nullptr;
    const int aoff = rA * 32 + k0;       // LDS short index; j adds 32*32j

    const size_t ldbB = (size_t)ldb * 2;
    const char* gB[2]; int lB[2];
#pragma unroll
    for (int j = 0; j < 2; j++) {
        int o = (w * 2 + j) * 1024 + lane * 16;
        gB[j] = (const char*)Bt + (size_t)(nb0 + (o >> 6)) * ldbB + (o & 63);
        lB[j] = (w * 2 + j) * 512;
    }

    float4 fv[4];
    auto loadA = [&](int kt) {
#pragma unroll
        for (int j = 0; j < 4; j++) {
            fv[j] = *(const float4*)(gA + (size_t)(j * 32) * lda + kt);
            if (ADD) {
                float4 t = *(const float4*)(gA2 + (size_t)(j * 32) * lda + kt);
                fv[j].x += t.x; fv[j].y += t.y; fv[j].z += t.z; fv[j].w += t.w;
            }
        }
    };
    auto writeA = [&](short* dstbuf) {
#pragma unroll
        for (int j = 0; j < 4; j++)
            *(bh4*)&dstbuf[j * 1024 + aoff] = pack4(fv[j]);   // 32 rows * 32 k
    };

    // prologue: tile 0 -> regs -> LDS buf0; B tile 0 -> LDS buf0
    loadA(0);
#pragma unroll
    for (int j = 0; j < 2; j++) gld_lds16(gB[j], &Bs[lB[j]]);
    writeA(As);

#pragma unroll 8
    for (int it = 0; it < NIT; ++it) {
        __syncthreads();
        const int cb = it & 1;
        const bool more = (it + 1 < NIT);
        if (more) {
            loadA((it + 1) * 32);
#pragma unroll
            for (int j = 0; j < 2; j++)
                gld_lds16(gB[j] + (size_t)(it + 1) * 64, &Bs[(cb ^ 1) * 128 * 32 + lB[j]]);
        }
        const short* Ab = &As[cb * 128 * 32];
        const short* Bb = &Bs[cb * 128 * 32];
        bf16x8 af[2];
        af[0] = *(const bf16x8*)&Ab[(w * 32      + l15) * 32 + quad * 8];
        af[1] = *(const bf16x8*)&Ab[(w * 32 + 16 + l15) * 32 + quad * 8];
#pragma unroll
        for (int ni = 0; ni < 8; ni++) {
            bf16x8 bfr = *(const bf16x8*)&Bb[(ni * 16 + l15) * 32 + quad * 8];
            acc[0][ni] = __builtin_amdgcn_mfma_f32_16x16x32_bf16(af[0], bfr, acc[0][ni], 0, 0, 0);
            acc[1][ni] = __builtin_amdgcn_mfma_f32_16x16x32_bf16(af[1], bfr, acc[1][ni], 0, 0, 0);
        }
        if (more) writeA(&As[(cb ^ 1) * 128 * 32]);
    }
}

// ---------------------------------------------------------------------------
// Generic GEMM. EPI: 0 = f32 (+bias); 1 = bf16 (+bias); 2 = relu -> bf16.
// ---------------------------------------------------------------------------
template<int BM, int BN, int K, int EPI>
__global__ __launch_bounds__(256)
void mfma_gemm(const __hip_bfloat16* __restrict__ A,
               const __hip_bfloat16* __restrict__ Bt,
               const float* __restrict__ bias,
               float* __restrict__ outf, __hip_bfloat16* __restrict__ outb,
               int lda, int ldb, int ldOut)
{
    constexpr int NT = BN / 16, AF = BM / 64;
    __shared__ alignas(16) short As[2 * BM * 32];
    __shared__ alignas(16) short Bs[2 * BN * 32];

    const int tid = threadIdx.x, w = tid >> 6, lane = tid & 63;
    const int quad = lane >> 4, l15 = lane & 15;
    const int row0 = blockIdx.x * BM, nb0 = blockIdx.y * BN;

    floatx4 acc[AF][NT];
#pragma unroll
    for (int mi = 0; mi < AF; mi++)
#pragma unroll
        for (int ni = 0; ni < NT; ni++) acc[mi][ni] = (floatx4){0.f, 0.f, 0.f, 0.f};

    gemm_core<BM, BN, K>(A, Bt, row0, nb0, lda, ldb, As, Bs, acc);

    float bias_c[NT];
#pragma unroll
    for (int ni = 0; ni < NT; ni++) bias_c[ni] = bias ? bias[nb0 + ni * 16 + l15] : 0.f;

#pragma unroll
    for (int mi = 0; mi < AF; mi++)
#pragma unroll
        for (int r = 0; r < 4; r++) {
            int row = row0 + w * (AF * 16) + mi * 16 + quad * 4 + r;
            size_t rb = (size_t)row * ldOut + nb0;
#pragma unroll
            for (int ni = 0; ni < NT; ni++) {
                float v = acc[mi][ni][r] + bias_c[ni];
                if (EPI == 2)      outb[rb + ni * 16 + l15] = __float2bfloat16(fmaxf(v, 0.f));
                else if (EPI == 1) outb[rb + ni * 16 + l15] = __float2bfloat16(v);
                else               outf[rb + ni * 16 + l15] = v;
            }
        }
}

// ---------------------------------------------------------------------------
// Merged value-projection + off/attn GEMM, f32 A with fused cvt staging (v2).
// grid = (VTILES + 128, 3). x < VTILES: value = src @ Wv (y<2, bf16 out).
// x >= VTILES: (tgt+qpos) @ [W_off^T ++ W_attn^T] (y<2 off f32; y==2 softmax).
// ---------------------------------------------------------------------------
__global__ __launch_bounds__(256)
void mfma_gemm_vq(const float* __restrict__ src,
                  const __hip_bfloat16* __restrict__ Wvt,
                  const float* __restrict__ b_value,
                  __hip_bfloat16* __restrict__ valueb,
                  const float* __restrict__ tgt, const float* __restrict__ qpos,
                  const __hip_bfloat16* __restrict__ Woat,
                  const float* __restrict__ b_off, const float* __restrict__ b_attn,
                  float* __restrict__ offb, float* __restrict__ attnb)
{
    __shared__ alignas(16) short As[2 * 128 * 32];
    __shared__ alignas(16) short Bs[2 * 128 * 32];

    const bool isV = blockIdx.x < VTILES;
    if (isV && blockIdx.y == 2) return;

    const int tid = threadIdx.x, w = tid >> 6, lane = tid & 63;
    const int quad = lane >> 4, l15 = lane & 15;
    const int nb0 = blockIdx.y * 128;

    floatx4 acc[2][8];
#pragma unroll
    for (int mi = 0; mi < 2; mi++)
#pragma unroll
        for (int ni = 0; ni < 8; ni++) acc[mi][ni] = (floatx4){0.f, 0.f, 0.f, 0.f};

    if (isV) {
        const int row0 = blockIdx.x * 128;
        gemm_core_cvtA<256, false>(src, nullptr, Wvt, row0, nb0, 256, 256, As, Bs, acc);
        float bias_c[8];
#pragma unroll
        for (int ni = 0; ni < 8; ni++) bias_c[ni] = b_value[nb0 + ni * 16 + l15];
#pragma unroll
        for (int mi = 0; mi < 2; mi++)
#pragma unroll
            for (int r = 0; r < 4; r++) {
                int row = row0 + w * 32 + mi * 16 + quad * 4 + r;
                size_t rb = (size_t)row * 256 + nb0;
#pragma unroll
                for (int ni = 0; ni < 8; ni++)
                    valueb[rb + ni * 16 + l15] = __float2bfloat16(acc[mi][ni][r] + bias_c[ni]);
            }
        return;
    }

    const int row0 = (blockIdx.x - VTILES) * 128;
    gemm_core_cvtA<256, true>(tgt, qpos, Woat, row0, nb0, 256, 256, As, Bs, acc);

    if (blockIdx.y < 2) {    // offsets, f32, ld 256
        float bias_c[8];
#pragma unroll
        for (int ni = 0; ni < 8; ni++) bias_c[ni] = b_off[nb0 + ni * 16 + l15];
#pragma unroll
        for (int mi = 0; mi < 2; mi++)
#pragma unroll
            for (int r = 0; r < 4; r++) {
                int row = row0 + w * 32 + mi * 16 + quad * 4 + r;
                size_t rb = (size_t)row * 256 + nb0;
#pragma unroll
                for (int ni = 0; ni < 8; ni++)
                    offb[rb + ni * 16 + l15] = acc[mi][ni][r] + bias_c[ni];
            }
    } else {                 // attn: group-softmax(16) -> ld 128
        float bias_c[8];
#pragma unroll
        for (int ni = 0; ni < 8; ni++) bias_c[ni] = b_attn[ni * 16 + l15];
#pragma unroll
        for (int mi = 0; mi < 2; mi++)
#pragma unroll
            for (int r = 0; r < 4; r++) {
                int row = row0 + w * 32 + mi * 16 + quad * 4 + r;
                size_t rb = (size_t)row * 128;
#pragma unroll
                for (int ni = 0; ni < 8; ni++) {
                    float v = acc[mi][ni][r] + bias_c[ni];
                    float m = v;
#pragma unroll
                    for (int msk = 1; msk <= 8; msk <<= 1) m = fmaxf(m, __shfl_xor(m, msk));
                    float e = __expf(v - m);
                    float ssum = e;
#pragma unroll
                    for (int msk = 1; msk <= 8; msk <<= 1) ssum += __shfl_xor(ssum, msk);
                    attnb[rb + ni * 16 + l15] = e / ssum;
                }
            }
    }
}

// ---------------------------------------------------------------------------
// Residual + LayerNorm, one wave per 256-col row.
// v = resid + in1 (+ bias); out f32 (+ optional bf16 copy).
// B1: in1 is bf16 (in1b) instead of f32 (in1f).
// ---------------------------------------------------------------------------
template<bool B1>
__global__ __launch_bounds__(256)
void ln_kernel(const float* __restrict__ in1f, const __hip_bfloat16* __restrict__ in1b,
               const float* __restrict__ resid, const float* __restrict__ bias,
               const float* __restrict__ g, const float* __restrict__ b,
               float* __restrict__ outf, __hip_bfloat16* __restrict__ outb)
{
    const int row  = blockIdx.x * 4 + (threadIdx.x >> 6);
    const int lane = threadIdx.x & 63;
    const size_t rb = (size_t)row * 256 + lane * 4;

    float4 v = *(const float4*)(resid + rb);
    if (B1) {
        bh4 a = *(const bh4*)(in1b + rb);
        v.x += __bfloat162float(a.a); v.y += __bfloat162float(a.b);
        v.z += __bfloat162float(a.c); v.w += __bfloat162float(a.d);
    } else {
        float4 a = *(const float4*)(in1f + rb);
        v.x += a.x; v.y += a.y; v.z += a.z; v.w += a.w;
    }
    if (bias) {
        float4 c = *(const float4*)(bias + lane * 4);
        v.x += c.x; v.y += c.y; v.z += c.z; v.w += c.w;
    }
    float s  = v.x + v.y + v.z + v.w;
    float sq = v.x * v.x + v.y * v.y + v.z * v.z + v.w * v.w;
#pragma unroll
    for (int msk = 1; msk <= 32; msk <<= 1) {
        s += __shfl_xor(s, msk); sq += __shfl_xor(sq, msk);
    }
    float mean = s * (1.f / 256.f);
    float var  = sq * (1.f / 256.f) - mean * mean;
    float rstd = rsqrtf(var + 1e-5f);
    float4 gg = *(const float4*)(g + lane * 4);
    float4 bb = *(const float4*)(b + lane * 4);
    float4 o;
    o.x = (v.x - mean) * rstd * gg.x + bb.x;
    o.y = (v.y - mean) * rstd * gg.y + bb.y;
    o.z = (v.z - mean) * rstd * gg.z + bb.z;
    o.w = (v.w - mean) * rstd * gg.w + bb.w;
    *(float4*)(outf + rb) = o;
    if (outb)
        *(bh4*)(outb + rb) = { __float2bfloat16(o.x), __float2bfloat16(o.y),
                               __float2bfloat16(o.z), __float2bfloat16(o.w) };
}

// ---------------------------------------------------------------------------
// Prep: weight transpose + f32->bf16 only (736 tiles of 32x32)
// ---------------------------------------------------------------------------
__global__ __launch_bounds__(256)
void prep_kernel(const float* w0, const float* w1, const float* w2,
                 const float* w3, const float* w4, const float* w5,
                 __hip_bfloat16* o0, __hip_bfloat16* o1, __hip_bfloat16* o2,
                 __hip_bfloat16* o3, __hip_bfloat16* o4, __hip_bfloat16* o5)
{
    int t = blockIdx.x;
    const float* s; __hip_bfloat16* dst; int Kd, Nd, tl;
    if      (t < 64)  { s = w0; dst = o0; Kd = 256;  Nd = 256;  tl = t; }
    else if (t < 128) { s = w1; dst = o1; Kd = 256;  Nd = 256;  tl = t - 64; }
    else if (t < 160) { s = w2; dst = o2; Kd = 256;  Nd = 128;  tl = t - 128; }
    else if (t < 224) { s = w3; dst = o3; Kd = 256;  Nd = 256;  tl = t - 160; }
    else if (t < 480) { s = w4; dst = o4; Kd = 256;  Nd = 1024; tl = t - 224; }
    else              { s = w5; dst = o5; Kd = 1024; Nd = 256;  tl = t - 480; }
    int ntn = Nd >> 5;
    int kt = tl / ntn, nt = tl - kt * ntn;
    __shared__ float T[32][33];
    int tx = threadIdx.x & 31, ty = threadIdx.x >> 5;
#pragma unroll
    for (int i = 0; i < 4; i++) {
        int k = kt * 32 + ty + i * 8;
        T[tx][ty + i * 8] = s[(size_t)k * Nd + nt * 32 + tx];
    }
    __syncthreads();
#pragma unroll
    for (int i = 0; i < 4; i++) {
        int n = nt * 32 + ty + i * 8;
        dst[(size_t)n * Kd + kt * 32 + tx] = __float2bfloat16(T[ty + i * 8][tx]);
    }
}

// ---------------------------------------------------------------------------
// Deformable bilinear sampling v5. Block = 8 queries, LDS 4B/entry
// ([31:16] pixel row, [15:0] weight fp16), stride-65 layout (conflict-free).
// Phase 2: thread=(ql,h,d4) gathers 8 channels per 16B load, explicit
// 16-deep load batching.
// ---------------------------------------------------------------------------
#define QB 8
__global__ __launch_bounds__(256, 4)
void sample_kernel(const float* __restrict__ refp, const float* __restrict__ offb,
                   const float* __restrict__ attn,
                   const __hip_bfloat16* __restrict__ value,
                   __hip_bfloat16* __restrict__ tgt2)
{
    __shared__ unsigned spk[64 * 65];       // [sc=lp*4+c][g=ql*8+h]

    const int q0  = blockIdx.x * QB;
    const int tid = threadIdx.x;

    // ---- phase 1 ----
#pragma unroll
    for (int k = 0; k < 4; k++) {
        const int it = tid + k * 256;        // (ql,h,lp)
        const int ql = it >> 7, h = (it >> 4) & 7, lp = it & 15;
        const int l = lp >> 2, p = lp & 3;
        const int q = q0 + ql, b = q >> 13;
        const int Wl = 128 >> l;
        const int LST = (l == 0) ? 0 : (l == 1) ? 16384 : (l == 2) ? 20480 : 21504;

        const float rx = refp[((size_t)q * N_LEVELS + l) * 2 + 0];
        const float ry = refp[((size_t)q * N_LEVELS + l) * 2 + 1];
        const float ox = offb[(size_t)q * 256 + h * 32 + l * 8 + p * 2 + 0];
        const float oy = offb[(size_t)q * 256 + h * 32 + l * 8 + p * 2 + 1];
        const float a  = attn[(size_t)q * 128 + h * 16 + lp];

        const float x = rx * Wl - 0.5f + ox;
        const float y = ry * Wl - 0.5f + oy;
        const float x0f = floorf(x), y0f = floorf(y);
        const float wx = x - x0f, wy = y - y0f;
        const int ix = (int)x0f, iy = (int)y0f;
        const int base = b * S_TOTAL + LST;
        const int g = ql * 8 + h;
        const float cw[4] = {(1.f - wx) * (1.f - wy) * a, wx * (1.f - wy) * a,
                             (1.f - wx) * wy * a,         wx * wy * a};
#pragma unroll
        for (int c = 0; c < 4; c++) {
            const int xi = ix + (c & 1), yi = iy + (c >> 1);
            const bool valid = ((unsigned)xi < (unsigned)Wl) && ((unsigned)yi < (unsigned)Wl);
            const unsigned pix = valid ? (unsigned)(base + yi * Wl + xi) : (unsigned)base;
            const __half hw = __float2half(valid ? cw[c] : 0.f);
            spk[(lp * 4 + c) * 65 + g] = (pix << 16) | (unsigned)__half_as_ushort(hw);
        }
    }
    __syncthreads();

    // ---- phase 2: 4 batches of 16 gathers, loads issued 16-deep ----
    const int ql = tid >> 5, h = (tid >> 2) & 7, d4 = tid & 3;
    const int q = q0 + ql, g = ql * 8 + h;
    const int c0 = h * 32 + d4 * 8;
    const char* vb = (const char*)value + (size_t)c0 * 2;

    float ac[8] = {0.f, 0.f, 0.f, 0.f, 0.f, 0.f, 0.f, 0.f};
#pragma unroll
    for (int ch = 0; ch < 4; ch++) {
        unsigned us[16];
#pragma unroll
        for (int j = 0; j < 16; j++) us[j] = spk[(ch * 16 + j) * 65 + g];
        uint4 rv[16];
#pragma unroll
        for (int j = 0; j < 16; j++)
            rv[j] = *(const uint4*)(vb + ((size_t)(us[j] >> 16) << 9));
#pragma unroll
        for (int j = 0; j < 16; j++) {
            float wv = __half2float(__ushort_as_half((unsigned short)(us[j] & 0xffffu)));
            ac[0] += wv * __uint_as_float(rv[j].x << 16);
            ac[1] += wv * __uint_as_float(rv[j].x & 0xffff0000u);
            ac[2] += wv * __uint_as_float(rv[j].y << 16);
            ac[3] += wv * __uint_as_float(rv[j].y & 0xffff0000u);
            ac[4] += wv * __uint_as_float(rv[j].z << 16);
            ac[5] += wv * __uint_as_float(rv[j].z & 0xffff0000u);
            ac[6] += wv * __uint_as_float(rv[j].w << 16);
            ac[7] += wv * __uint_as_float(rv[j].w & 0xffff0000u);
        }
    }
    bh8 o;
#pragma unroll
    for (int i = 0; i < 8; i++) o.v[i] = __float2bfloat16(ac[i]);
    *(bh8*)(tgt2 + (size_t)q * 256 + c0) = o;
}

// ---------------------------------------------------------------------------
extern "C" void kernel_launch(void* const* d_in, const int* in_sizes, int n_in,
                              void* d_out, int out_size, void* d_ws, size_t ws_size,
                              hipStream_t stream) {
    const float* tgt     = (const float*)d_in[0];
    const float* qpos    = (const float*)d_in[1];
    const float* refp    = (const float*)d_in[2];
    const float* src     = (const float*)d_in[3];
    const float* W_value = (const float*)d_in[6];
    const float* b_value = (const float*)d_in[7];
    const float* W_off   = (const float*)d_in[8];
    const float* b_off   = (const float*)d_in[9];
    const float* W_attn  = (const float*)d_in[10];
    const float* b_attn  = (const float*)d_in[11];
    const float* W_out   = (const float*)d_in[12];
    const float* b_out   = (const float*)d_in[13];
    const float* ln1_g   = (const float*)d_in[14];
    const float* ln1_b   = (const float*)d_in[15];
    const float* W1      = (const float*)d_in[16];
    const float* b1      = (const float*)d_in[17];
    const float* W2      = (const float*)d_in[18];
    const float* b2      = (const float*)d_in[19];
    const float* ln3_g   = (const float*)d_in[20];
    const float* ln3_b   = (const float*)d_in[21];
    float* out = (float*)d_out;

    // workspace layout
    char* p = (char*)d_ws;
    auto nxt = [&](size_t b) { char* r = p; p += (b + 255) & ~(size_t)255; return r; };
    __hip_bfloat16* Wvt    = (__hip_bfloat16*)nxt((size_t)256 * 256 * 2);
    __hip_bfloat16* Woat   = (__hip_bfloat16*)nxt((size_t)384 * 256 * 2);
    __hip_bfloat16* Woutt  = (__hip_bfloat16*)nxt((size_t)256 * 256 * 2);
    __hip_bfloat16* W1t    = (__hip_bfloat16*)nxt((size_t)1024 * 256 * 2);
    __hip_bfloat16* W2t    = (__hip_bfloat16*)nxt((size_t)256 * 1024 * 2);
    __hip_bfloat16* valueb = (__hip_bfloat16*)nxt((size_t)M_V * 256 * 2);  // dead after sampler
    float*          offb   = (float*)nxt((size_t)M_Q * 256 * 4);           // dead after sampler
    float*          attnb  = (float*)nxt((size_t)M_Q * 128 * 4);
    __hip_bfloat16* tgt2b  = (__hip_bfloat16*)nxt((size_t)M_Q * 256 * 2);
    __hip_bfloat16* t2ob   = (__hip_bfloat16*)nxt((size_t)M_Q * 256 * 2);
    float*          x      = (float*)nxt((size_t)M_Q * 256 * 4);
    __hip_bfloat16* xb     = (__hip_bfloat16*)nxt((size_t)M_Q * 256 * 2);
    __hip_bfloat16* hb     = (__hip_bfloat16*)nxt((size_t)M_Q * 1024 * 2);
    // FFN2 output (f32, 16.8 MB) overlays valueb (dead after sampler)
    float* f2o = (float*)valueb;

    dim3 blk(256);

    // 0) prep: weight transpose+cvt only
    prep_kernel<<<dim3(736), blk, 0, stream>>>(
        W_value, W_off, W_attn, W_out, W1, W2,
        Wvt, Woat, Woat + 256 * 256, Woutt, W1t, W2t);

    // 1) value GEMM ++ off/attn GEMM (f32 A, coalesced fused cvt staging)
    mfma_gemm_vq<<<dim3(VTILES + M_Q / 128, 3), blk, 0, stream>>>(
        src, Wvt, b_value, valueb, tgt, qpos, Woat, b_off, b_attn, offb, attnb);

    // 2) deformable sampling -> tgt2 (bf16)
    sample_kernel<<<dim3(M_Q / QB), blk, 0, stream>>>(refp, offb, attnb, valueb, tgt2b);

    // 3) t2o = tgt2 @ W_out + b_out -> bf16  (512 blocks)
    mfma_gemm<64, 128, 256, 1><<<dim3(M_Q / 64, 2), blk, 0, stream>>>(
        tgt2b, Woutt, b_out, nullptr, t2ob, 256, 256, 256);

    // 4) x = LN1(tgt + t2o) -> f32 + bf16
    ln_kernel<true><<<dim3(M_Q / 4), blk, 0, stream>>>(
        nullptr, t2ob, tgt, nullptr, ln1_g, ln1_b, x, xb);

    // 5) h = relu(x @ W1 + b1) -> bf16  (1024 blocks)
    mfma_gemm<128, 128, 256, 2><<<dim3(M_Q / 128, 8), blk, 0, stream>>>(
        xb, W1t, b1, nullptr, hb, 256, 256, 1024);

    // 6) f2o = h @ W2 + b2 -> f32, single pass K=1024 (512 blocks, 32 K-iters)
    mfma_gemm<64, 128, 1024, 0><<<dim3(M_Q / 64, 2), blk, 0, stream>>>(
        hb, W2t, b2, f2o, nullptr, 1024, 1024, 256);

    // 7) out = LN3(x + f2o) -> f32
    ln_kernel<false><<<dim3(M_Q / 4), blk, 0, stream>>>(
        f2o, nullptr, x, nullptr, ln3_g, ln3_b, out, nullptr);
}